// Round 16
// baseline (35.975 us; speedup 1.0000x reference)
//
#include <hip/hip_runtime.h>
#include <math.h>

#define HH 512
#define WW 512
#define NBC 24          // B*C = 8*3
#define TH 64
#define TW 32
#define RAD 4
#define NXT (WW / TW)                 // 16 x-tiles
#define NYT (HH / TH)                 // 8 y-tiles
#define NBLK (NXT * NYT * NBC)        // 3072
#define PI_F 3.14159265358979323846f
#define SMW 36          // LDS row stride (floats)

// Gaussian taps: exp(-0.5*x^2)/sum, x=-4..4 (double-computed, f32-rounded;
// <=1 ulp vs jnp's f32 path).
__device__ __constant__ float GW[9] = {
    1.3383023e-04f, 4.4318484e-03f, 5.3990968e-02f, 2.4197073e-01f,
    3.9894228e-01f, 2.4197073e-01f, 5.3990968e-02f, 4.4318484e-03f,
    1.3383023e-04f
};

__device__ __forceinline__ int reflect_y(int gy)
{
    return (gy < 0) ? (-gy - 1) : ((gy >= HH) ? (2 * HH - 1 - gy) : gy);
}

// |atan2(y,x)| in [0,pi], branchless, ~3e-7 max error, NaN-free.
__device__ __forceinline__ float abs_atan2_fast(float y, float x)
{
    float ax = fabsf(x), ay = fabsf(y);
    float mx = fmaxf(ax, ay), mn = fminf(ax, ay);
    float t = mn * __builtin_amdgcn_rcpf(fmaxf(mx, 1e-30f));
    float s = t * t;
    float r = -0.01172120f;
    r = fmaf(r, s, 0.05265332f);
    r = fmaf(r, s, -0.11643287f);
    r = fmaf(r, s, 0.19354346f);
    r = fmaf(r, s, -0.33262347f);
    r = fmaf(r, s, 0.99997726f);
    r = r * t;                                  // atan(mn/mx) in [0, pi/4]
    r = (ay > ax) ? (0.5f * PI_F - r) : r;      // undo octant swap
    r = (x < 0.f) ? (PI_F - r) : r;             // quadrant
    return r;
}

__device__ __forceinline__ float4 hblur12(int4 a, int4 b, int4 c)
{
    float win[12] = {
        (float)a.x, (float)a.y, (float)a.z, (float)a.w,
        (float)b.x, (float)b.y, (float)b.z, (float)b.w,
        (float)c.x, (float)c.y, (float)c.z, (float)c.w };
    float s0 = 0.f, s1 = 0.f, s2 = 0.f, s3 = 0.f;
    #pragma unroll
    for (int j = 0; j < 9; ++j) {
        float gw = GW[j];
        s0 = fmaf(gw, win[j],     s0);
        s1 = fmaf(gw, win[j + 1], s1);
        s2 = fmaf(gw, win[j + 2], s2);
        s3 = fmaf(gw, win[j + 3], s3);
    }
    return make_float4(s0, s1, s2, s3);
}

// 512 threads per 64x32 tile. Non-edge blocks use issue-early staging: ALL
// global loads (mask then o/t) issued into named registers before any use,
// pinned by an asm memory clobber; mask H-blur VALU overlaps the o/t loads'
// latency (counted vmcnt), ds_writes land late. One latency exposure/block.
__global__ __launch_bounds__(512) void egcl_fused(
    const float* __restrict__ outp,
    const float* __restrict__ tgtp,
    const int*   __restrict__ maskp,
    float*       __restrict__ partials)  // [3][NBLK]: w, mag, dir
{
    __shared__ __align__(16) float smh[TH + 8][SMW];  // 72 rows H-blurred mask
    __shared__ __align__(16) float oT[TH + 2][SMW];   // 66 rows
    __shared__ __align__(16) float tT[TH + 2][SMW];
    __shared__ float red[3][8];

    const int tid = threadIdx.x;

    // XCD-aware bijective swizzle: each XCD gets 3 contiguous z-planes
    const int bid = (int)blockIdx.x;
    const int nb  = (bid & 7) * (NBLK / 8) + (bid >> 3);
    const int xt  = nb & 15;            // x-tile fastest -> row-of-tiles locality
    const int yt  = (nb >> 4) & 7;
    const int z   = nb >> 7;
    const int y0  = yt * TH;
    const int x0  = xt * TW;
    const size_t plane = (size_t)z * (HH * WW);
    const bool xedge = (x0 == 0) || (x0 == WW - TW);

    if (!xedge) {
        // ==== Phase 1: issue mask loads (task0 all threads; task1 wave 0) ====
        const int r0  = tid >> 3;
        const int cg0 = (tid & 7) << 2;
        const int gy0 = reflect_y(y0 + r0 - RAD);
        const int* mr0 = maskp + plane + (size_t)gy0 * WW + x0 + cg0;
        int4 ma0 = *(const int4*)(mr0 - 4);
        int4 mb0 = *(const int4*)(mr0);
        int4 mc0 = *(const int4*)(mr0 + 4);

        const bool m2 = (tid < 64);          // wave-0-uniform
        int4 ma1 = ma0, mb1 = mb0, mc1 = mc0;
        int r1 = 0;
        if (m2) {
            r1 = 64 + (tid >> 3);
            const int gy1 = reflect_y(y0 + r1 - RAD);
            const int* mr1 = maskp + plane + (size_t)gy1 * WW + x0 + cg0;
            ma1 = *(const int4*)(mr1 - 4);
            mb1 = *(const int4*)(mr1);
            mc1 = *(const int4*)(mr1 + 4);
        }

        // ==== Phase 2: issue o/t loads (task0 all; task1 tid<82) ====
        const int ro0 = tid / 9, go0 = tid - ro0 * 9;
        const int gyo0 = y0 + ro0 - 1;
        const bool in0 = (gyo0 >= 0) && (gyo0 < HH);
        float4 vo0 = make_float4(0.f, 0.f, 0.f, 0.f), vt0 = vo0;
        if (in0) {
            const size_t rb = plane + (size_t)gyo0 * WW + (x0 - 1 + 4 * go0);
            vo0 = *(const float4*)&outp[rb];
            vt0 = *(const float4*)&tgtp[rb];
        }
        const bool o2 = (tid < 82);
        int ro1 = 0, go1 = 0;
        float4 vo1 = make_float4(0.f, 0.f, 0.f, 0.f), vt1 = vo1;
        if (o2) {
            const int i1 = 512 + tid;
            ro1 = i1 / 9; go1 = i1 - ro1 * 9;
            const int gyo1 = y0 + ro1 - 1;
            if (gyo1 < HH) {                 // ro1 >= 56 so gyo1 >= y0+55 >= 55
                const size_t rb = plane + (size_t)gyo1 * WW + (x0 - 1 + 4 * go1);
                vo1 = *(const float4*)&outp[rb];
                vt1 = *(const float4*)&tgtp[rb];
            }
        }

        // Pin: no memory op may cross; all loads stay issued above.
        asm volatile("" ::: "memory");

        // ==== Phase 3: mask H-blur VALU (overlaps o/t load latency) ====
        *(float4*)&smh[r0][cg0] = hblur12(ma0, mb0, mc0);
        if (m2) *(float4*)&smh[r1][cg0] = hblur12(ma1, mb1, mc1);

        // ==== Phase 4: o/t ds_writes (loads have arrived by now) ====
        *(float4*)&oT[ro0][4 * go0] = vo0;
        *(float4*)&tT[ro0][4 * go0] = vt0;
        if (o2) {
            *(float4*)&oT[ro1][4 * go1] = vo1;
            *(float4*)&tT[ro1][4 * go1] = vt1;
        }
    } else {
        // ---- edge blocks: R13 sequential scalar-reflect staging ----
        for (int i = tid; i < (TH + 8) * 8; i += 512) {
            int r = i >> 3, cg = (i & 7) << 2;
            int gy = reflect_y(y0 + r - RAD);
            const int* mrow = maskp + plane + (size_t)gy * WW;
            float win[12];
            #pragma unroll
            for (int k = 0; k < 12; ++k) {
                int gx = x0 + cg - 4 + k;
                gx = (gx < 0) ? (-gx - 1) : ((gx >= WW) ? (2 * WW - 1 - gx) : gx);
                win[k] = (float)mrow[gx];
            }
            float s0 = 0.f, s1 = 0.f, s2 = 0.f, s3 = 0.f;
            #pragma unroll
            for (int j = 0; j < 9; ++j) {
                float gw = GW[j];
                s0 = fmaf(gw, win[j],     s0);
                s1 = fmaf(gw, win[j + 1], s1);
                s2 = fmaf(gw, win[j + 2], s2);
                s3 = fmaf(gw, win[j + 3], s3);
            }
            *(float4*)&smh[r][cg] = make_float4(s0, s1, s2, s3);
        }
        for (int i = tid; i < (TH + 2) * 9; i += 512) {
            int r = i / 9, g = i - r * 9;
            int gy = y0 + r - 1;
            bool rowin = (gy >= 0) && (gy < HH);
            float4 vo = make_float4(0.f, 0.f, 0.f, 0.f);
            float4 vt = vo;
            if (rowin) {
                const size_t rowbase = plane + (size_t)gy * WW;
                float a[4], b[4];
                #pragma unroll
                for (int k = 0; k < 4; ++k) {
                    int gx = x0 - 1 + 4 * g + k;
                    bool in = (gx >= 0) && (gx < WW);
                    size_t idx = rowbase + (in ? gx : 0);
                    a[k] = in ? outp[idx] : 0.f;
                    b[k] = in ? tgtp[idx] : 0.f;
                }
                vo = make_float4(a[0], a[1], a[2], a[3]);
                vt = make_float4(b[0], b[1], b[2], b[3]);
            }
            *(float4*)&oT[r][4 * g] = vo;
            *(float4*)&tT[r][4 * g] = vt;
        }
    }
    __syncthreads();   // the ONLY mid-kernel barrier

    // ---- compute: thread owns 1 row x 4 cols ----
    const int r  = tid >> 3;            // 0..63
    const int c4 = (tid & 7) << 2;      // 0..28

    // V-blur over 9 smh rows -> weights
    float4 a0 = make_float4(0.f, 0.f, 0.f, 0.f);
    #pragma unroll
    for (int j = 0; j < 9; ++j) {
        float4 m = *(const float4*)&smh[r + j][c4];
        float gw = GW[j];
        a0.x = fmaf(gw, m.x, a0.x); a0.y = fmaf(gw, m.y, a0.y);
        a0.z = fmaf(gw, m.z, a0.z); a0.w = fmaf(gw, m.w, a0.w);
    }
    float wgt[4];
    {
        float smv[4] = {a0.x, a0.y, a0.z, a0.w};
        #pragma unroll
        for (int i = 0; i < 4; ++i) {
            float sm = fminf(fmaxf(smv[i], 0.f), 1.f);
            float w = 1.f - fabsf(sm - 0.5f) * 2.f;
            wgt[i] = fminf(fmaxf(w, 0.f), 1.f);
        }
    }

    // Sobel: 3 LDS rows x 6 cols per image
    float ao[6], bo[6], co[6], at[6], bt[6], ct[6];
    *(float4*)&ao[0] = *(const float4*)&oT[r    ][c4];
    *(float2*)&ao[4] = *(const float2*)&oT[r    ][c4 + 4];
    *(float4*)&bo[0] = *(const float4*)&oT[r + 1][c4];
    *(float2*)&bo[4] = *(const float2*)&oT[r + 1][c4 + 4];
    *(float4*)&co[0] = *(const float4*)&oT[r + 2][c4];
    *(float2*)&co[4] = *(const float2*)&oT[r + 2][c4 + 4];
    *(float4*)&at[0] = *(const float4*)&tT[r    ][c4];
    *(float2*)&at[4] = *(const float2*)&tT[r    ][c4 + 4];
    *(float4*)&bt[0] = *(const float4*)&tT[r + 1][c4];
    *(float2*)&bt[4] = *(const float2*)&tT[r + 1][c4 + 4];
    *(float4*)&ct[0] = *(const float4*)&tT[r + 2][c4];
    *(float2*)&ct[4] = *(const float2*)&tT[r + 2][c4 + 4];

    // separable Sobel: t = a+2b+c (gx = t[i+2]-t[i]); u = c-a (gy = u[i]+2u[i+1]+u[i+2])
    float to_[6], uo[6], tt_[6], ut[6];
    #pragma unroll
    for (int j = 0; j < 6; ++j) {
        to_[j] = fmaf(2.f, bo[j], ao[j] + co[j]);
        uo[j]  = co[j] - ao[j];
        tt_[j] = fmaf(2.f, bt[j], at[j] + ct[j]);
        ut[j]  = ct[j] - at[j];
    }

    float s_w = 0.f, s_mag = 0.f, s_dir = 0.f;
    #pragma unroll
    for (int i = 0; i < 4; ++i) {
        float xo = to_[i + 2] - to_[i];
        float yo = fmaf(2.f, uo[i + 1], uo[i] + uo[i + 2]);
        float xt_ = tt_[i + 2] - tt_[i];
        float yt_ = fmaf(2.f, ut[i + 1], ut[i] + ut[i + 2]);

        float mago = __builtin_amdgcn_sqrtf(fmaf(xo, xo, fmaf(yo, yo, 1e-8f)));
        float magt = __builtin_amdgcn_sqrtf(fmaf(xt_, xt_, fmaf(yt_, yt_, 1e-8f)));
        float cross = yo * xt_ - xo * yt_;
        float dotp  = fmaf(xo, xt_, yo * yt_);
        float dd = abs_atan2_fast(cross, dotp);
        float w = wgt[i];
        s_w   += w;
        s_mag += w * fabsf(mago - magt);
        s_dir += dd * w;
    }

    // ---- block reduction (8 waves) ----
    #pragma unroll
    for (int o = 32; o > 0; o >>= 1) {
        s_w   += __shfl_down(s_w,   o, 64);
        s_mag += __shfl_down(s_mag, o, 64);
        s_dir += __shfl_down(s_dir, o, 64);
    }
    const int wid = tid >> 6;
    if ((tid & 63) == 0) { red[0][wid] = s_w; red[1][wid] = s_mag; red[2][wid] = s_dir; }
    __syncthreads();
    if (tid == 0) {
        float p0 = 0.f, p1 = 0.f, p2 = 0.f;
        #pragma unroll
        for (int k = 0; k < 8; ++k) { p0 += red[0][k]; p1 += red[1][k]; p2 += red[2][k]; }
        partials[bid]            = p0;
        partials[NBLK + bid]     = p1;
        partials[2 * NBLK + bid] = p2;
    }
}

__global__ __launch_bounds__(256) void egcl_finalize(
    const float* __restrict__ partials, float* __restrict__ out)
{
    __shared__ double red[3][4];
    const int tid = threadIdx.x;
    double s0 = 0.0, s1 = 0.0, s2 = 0.0;
    const float4* p0 = (const float4*)partials;
    const float4* p1 = (const float4*)(partials + NBLK);
    const float4* p2 = (const float4*)(partials + 2 * NBLK);
    for (int i = tid; i < NBLK / 4; i += 256) {
        float4 a = p0[i], b = p1[i], c = p2[i];
        s0 += (double)a.x + (double)a.y + (double)a.z + (double)a.w;
        s1 += (double)b.x + (double)b.y + (double)b.z + (double)b.w;
        s2 += (double)c.x + (double)c.y + (double)c.z + (double)c.w;
    }
    #pragma unroll
    for (int o = 32; o > 0; o >>= 1) {
        s0 += __shfl_down(s0, o, 64);
        s1 += __shfl_down(s1, o, 64);
        s2 += __shfl_down(s2, o, 64);
    }
    const int wid = tid >> 6;
    if ((tid & 63) == 0) { red[0][wid] = s0; red[1][wid] = s1; red[2][wid] = s2; }
    __syncthreads();
    if (tid == 0) {
        double Sw   = red[0][0] + red[0][1] + red[0][2] + red[0][3];
        double Smag = red[1][0] + red[1][1] + red[1][2] + red[1][3];
        double Sdir = red[2][0] + red[2][1] + red[2][2] + red[2][3];
        const double N = (double)NBC * HH * WW;
        double mag_loss = Smag / N;
        if (Sw > 0.0) mag_loss = mag_loss / (Sw / N + 1e-8);
        double dir_loss = Sdir;
        if (Sw > 0.0) dir_loss = Sdir / (Sw + 1e-8);
        out[0] = (float)(mag_loss + dir_loss);
    }
}

extern "C" void kernel_launch(void* const* d_in, const int* in_sizes, int n_in,
                              void* d_out, int out_size, void* d_ws, size_t ws_size,
                              hipStream_t stream)
{
    const float* outp = (const float*)d_in[0];
    const float* tgtp = (const float*)d_in[1];
    const int*   maskp = (const int*)d_in[2];
    float* partials = (float*)d_ws;

    egcl_fused<<<dim3(NBLK, 1, 1), 512, 0, stream>>>(outp, tgtp, maskp, partials);
    egcl_finalize<<<1, 256, 0, stream>>>(partials, (float*)d_out);
}

// Round 17
// 35.108 us; speedup vs baseline: 1.0247x; 1.0247x over previous
//
#include <hip/hip_runtime.h>
#include <math.h>

#define HH 512
#define WW 512
#define NBC 24          // B*C = 8*3
#define TH 64
#define TW 32
#define RAD 4
#define NXT (WW / TW)                 // 16 x-tiles
#define NYT (HH / TH)                 // 8 y-tiles
#define NBLK (NXT * NYT * NBC)        // 3072
#define PI_F 3.14159265358979323846f
#define SMW 36          // smh row stride (floats)
#define OTW 40          // oT/tT row stride; LDS col c <-> image col x0-4+c

// Gaussian taps: exp(-0.5*x^2)/sum, x=-4..4 (double-computed, f32-rounded;
// <=1 ulp vs jnp's f32 path).
__device__ __constant__ float GW[9] = {
    1.3383023e-04f, 4.4318484e-03f, 5.3990968e-02f, 2.4197073e-01f,
    3.9894228e-01f, 2.4197073e-01f, 5.3990968e-02f, 4.4318484e-03f,
    1.3383023e-04f
};

__device__ __forceinline__ int reflect_y(int gy)
{
    return (gy < 0) ? (-gy - 1) : ((gy >= HH) ? (2 * HH - 1 - gy) : gy);
}

// |atan2(y,x)| in [0,pi], branchless, ~3e-7 max error, NaN-free.
__device__ __forceinline__ float abs_atan2_fast(float y, float x)
{
    float ax = fabsf(x), ay = fabsf(y);
    float mx = fmaxf(ax, ay), mn = fminf(ax, ay);
    float t = mn * __builtin_amdgcn_rcpf(fmaxf(mx, 1e-30f));
    float s = t * t;
    float r = -0.01172120f;
    r = fmaf(r, s, 0.05265332f);
    r = fmaf(r, s, -0.11643287f);
    r = fmaf(r, s, 0.19354346f);
    r = fmaf(r, s, -0.33262347f);
    r = fmaf(r, s, 0.99997726f);
    r = r * t;                                  // atan(mn/mx) in [0, pi/4]
    r = (ay > ax) ? (0.5f * PI_F - r) : r;      // undo octant swap
    r = (x < 0.f) ? (PI_F - r) : r;             // quadrant
    return r;
}

__device__ __forceinline__ float4 hblur12(int4 a, int4 b, int4 c)
{
    float win[12] = {
        (float)a.x, (float)a.y, (float)a.z, (float)a.w,
        (float)b.x, (float)b.y, (float)b.z, (float)b.w,
        (float)c.x, (float)c.y, (float)c.z, (float)c.w };
    float s0 = 0.f, s1 = 0.f, s2 = 0.f, s3 = 0.f;
    #pragma unroll
    for (int j = 0; j < 9; ++j) {
        float gw = GW[j];
        s0 = fmaf(gw, win[j],     s0);
        s1 = fmaf(gw, win[j + 1], s1);
        s2 = fmaf(gw, win[j + 2], s2);
        s3 = fmaf(gw, win[j + 3], s3);
    }
    return make_float4(s0, s1, s2, s3);
}

// async 16B global -> LDS (wave-uniform LDS base + lane*16; per-lane gsrc)
__device__ __forceinline__ void gload_lds16(const float* gsrc, float* ldst)
{
    __builtin_amdgcn_global_load_lds(
        (const __attribute__((address_space(1))) void*)gsrc,
        (__attribute__((address_space(3))) void*)ldst, 16, 0, 0);
}

// 512 threads per 64x32 tile. o/t tiles staged via global_load_lds DMA
// (no VGPR round-trip, cannot be sunk by RA); mask H-blur VALU overlaps the
// DMA flight; one barrier.
__global__ __launch_bounds__(512) void egcl_fused(
    const float* __restrict__ outp,
    const float* __restrict__ tgtp,
    const int*   __restrict__ maskp,
    float*       __restrict__ partials)  // [3][NBLK]: w, mag, dir
{
    __shared__ __align__(16) float smh[TH + 8][SMW];  // 72 rows H-blurred mask
    __shared__ __align__(16) float oT[TH + 2][OTW];   // 66 rows x 40 cols
    __shared__ __align__(16) float tT[TH + 2][OTW];
    __shared__ float red[3][8];

    const int tid  = threadIdx.x;
    const int wv   = tid >> 6;
    const int lane = tid & 63;

    // XCD-aware bijective swizzle: each XCD gets 3 contiguous z-planes
    const int bid = (int)blockIdx.x;
    const int nb  = (bid & 7) * (NBLK / 8) + (bid >> 3);
    const int xt  = nb & 15;            // x-tile fastest -> row-of-tiles locality
    const int yt  = (nb >> 4) & 7;
    const int z   = nb >> 7;
    const int y0  = yt * TH;
    const int x0  = xt * TW;
    const size_t plane = (size_t)z * (HH * WW);
    const bool xedge = (x0 == 0) || (x0 == WW - TW);

    if (!xedge) {
        // ==== A: mask loads into regs (task0 all threads; task1 wave 0) ====
        const int r0  = tid >> 3;
        const int cg0 = (tid & 7) << 2;
        const int gy0 = reflect_y(y0 + r0 - RAD);
        const int* mr0 = maskp + plane + (size_t)gy0 * WW + x0 + cg0;
        int4 ma0 = *(const int4*)(mr0 - 4);
        int4 mb0 = *(const int4*)(mr0);
        int4 mc0 = *(const int4*)(mr0 + 4);
        const bool m2 = (tid < 64);
        int4 ma1 = ma0, mb1 = mb0, mc1 = mc0;
        int r1 = 0;
        if (m2) {
            r1 = 64 + (tid >> 3);
            const int gy1 = reflect_y(y0 + r1 - RAD);
            const int* mr1 = maskp + plane + (size_t)gy1 * WW + x0 + cg0;
            ma1 = *(const int4*)(mr1 - 4);
            mb1 = *(const int4*)(mr1);
            mc1 = *(const int4*)(mr1 + 4);
        }
        asm volatile("" ::: "memory");   // mask loads stay above the DMA

        // ==== B: issue o/t DMA. 660 float4 tasks per buffer, 11 segs/wave-set ====
        float* oTf = &oT[0][0];
        float* tTf = &tT[0][0];
        for (int seg = wv; seg < 11; seg += 8) {
            int t = (seg << 6) + lane;
            if (t < 660) {
                int rr = t / 10, g = t - 10 * rr;
                int gy = y0 + rr - 1;
                gy = (gy < 0) ? 0 : ((gy >= HH) ? (HH - 1) : gy);  // junk rows fixed later
                const size_t off = plane + (size_t)gy * WW + (x0 - 4 + (g << 2));
                gload_lds16(outp + off, oTf + (seg << 8));
                gload_lds16(tgtp + off, tTf + (seg << 8));
            }
        }

        // ==== C: mask H-blur + smh writes (overlaps DMA flight) ====
        *(float4*)&smh[r0][cg0] = hblur12(ma0, mb0, mc0);
        if (m2) *(float4*)&smh[r1][cg0] = hblur12(ma1, mb1, mc1);

        // ==== D: drain own DMAs, zero the (at most 2) out-of-range halo rows ====
        asm volatile("s_waitcnt vmcnt(0)" ::: "memory");
        if (y0 == 0 && wv == 0 && lane < 10) {            // row 0 in seg 0 (wave 0)
            *(float4*)&oT[0][lane << 2] = make_float4(0.f, 0.f, 0.f, 0.f);
            *(float4*)&tT[0][lane << 2] = make_float4(0.f, 0.f, 0.f, 0.f);
        }
        if (y0 + TH == HH && wv == 2 && lane < 10) {      // row 65 in seg 10 (wave 2)
            *(float4*)&oT[TH + 1][lane << 2] = make_float4(0.f, 0.f, 0.f, 0.f);
            *(float4*)&tT[TH + 1][lane << 2] = make_float4(0.f, 0.f, 0.f, 0.f);
        }
    } else {
        // ---- edge blocks: sequential scalar-reflect staging ----
        for (int i = tid; i < (TH + 8) * 8; i += 512) {
            int r = i >> 3, cg = (i & 7) << 2;
            int gy = reflect_y(y0 + r - RAD);
            const int* mrow = maskp + plane + (size_t)gy * WW;
            float win[12];
            #pragma unroll
            for (int k = 0; k < 12; ++k) {
                int gx = x0 + cg - 4 + k;
                gx = (gx < 0) ? (-gx - 1) : ((gx >= WW) ? (2 * WW - 1 - gx) : gx);
                win[k] = (float)mrow[gx];
            }
            float s0 = 0.f, s1 = 0.f, s2 = 0.f, s3 = 0.f;
            #pragma unroll
            for (int j = 0; j < 9; ++j) {
                float gw = GW[j];
                s0 = fmaf(gw, win[j],     s0);
                s1 = fmaf(gw, win[j + 1], s1);
                s2 = fmaf(gw, win[j + 2], s2);
                s3 = fmaf(gw, win[j + 3], s3);
            }
            *(float4*)&smh[r][cg] = make_float4(s0, s1, s2, s3);
        }
        for (int i = tid; i < 660; i += 512) {
            int rr = i / 10, g = i - 10 * rr;
            int gy = y0 + rr - 1;
            bool rowin = (gy >= 0) && (gy < HH);
            float a[4], b[4];
            #pragma unroll
            for (int k = 0; k < 4; ++k) {
                int gx = x0 - 4 + 4 * g + k;
                bool in = rowin && (gx >= 0) && (gx < WW);
                size_t idx = plane + (size_t)(rowin ? gy : 0) * WW + (in ? gx : 0);
                a[k] = in ? outp[idx] : 0.f;
                b[k] = in ? tgtp[idx] : 0.f;
            }
            *(float4*)&oT[rr][4 * g] = make_float4(a[0], a[1], a[2], a[3]);
            *(float4*)&tT[rr][4 * g] = make_float4(b[0], b[1], b[2], b[3]);
        }
    }
    __syncthreads();   // the ONLY mid-kernel barrier

    // ---- compute: thread owns 1 row x 4 cols ----
    const int r  = tid >> 3;            // 0..63
    const int c4 = (tid & 7) << 2;      // 0..28

    // V-blur over 9 smh rows -> weights
    float4 a0 = make_float4(0.f, 0.f, 0.f, 0.f);
    #pragma unroll
    for (int j = 0; j < 9; ++j) {
        float4 m = *(const float4*)&smh[r + j][c4];
        float gw = GW[j];
        a0.x = fmaf(gw, m.x, a0.x); a0.y = fmaf(gw, m.y, a0.y);
        a0.z = fmaf(gw, m.z, a0.z); a0.w = fmaf(gw, m.w, a0.w);
    }
    float wgt[4];
    {
        float smv[4] = {a0.x, a0.y, a0.z, a0.w};
        #pragma unroll
        for (int i = 0; i < 4; ++i) {
            float sm = fminf(fmaxf(smv[i], 0.f), 1.f);
            float w = 1.f - fabsf(sm - 0.5f) * 2.f;
            wgt[i] = fminf(fmaxf(w, 0.f), 1.f);
        }
    }

    // Sobel windows: aligned f2+f4+f2 per row; W[j][idx] = LDS col c4+2+idx,
    // image col x0+c4-2+idx; window k (0..5) = idx k+1.
    float Wo[3][8], Wt[3][8];
    #pragma unroll
    for (int j = 0; j < 3; ++j) {
        *(float2*)&Wo[j][0] = *(const float2*)&oT[r + j][c4 + 2];
        *(float4*)&Wo[j][2] = *(const float4*)&oT[r + j][c4 + 4];
        *(float2*)&Wo[j][6] = *(const float2*)&oT[r + j][c4 + 8];
        *(float2*)&Wt[j][0] = *(const float2*)&tT[r + j][c4 + 2];
        *(float4*)&Wt[j][2] = *(const float4*)&tT[r + j][c4 + 4];
        *(float2*)&Wt[j][6] = *(const float2*)&tT[r + j][c4 + 8];
    }

    // separable Sobel: t = a+2b+c (gx = t[i+2]-t[i]); u = c-a (gy = u[i]+2u[i+1]+u[i+2])
    float to_[6], uo[6], tt_[6], ut[6];
    #pragma unroll
    for (int j = 0; j < 6; ++j) {
        to_[j] = fmaf(2.f, Wo[1][j + 1], Wo[0][j + 1] + Wo[2][j + 1]);
        uo[j]  = Wo[2][j + 1] - Wo[0][j + 1];
        tt_[j] = fmaf(2.f, Wt[1][j + 1], Wt[0][j + 1] + Wt[2][j + 1]);
        ut[j]  = Wt[2][j + 1] - Wt[0][j + 1];
    }

    float s_w = 0.f, s_mag = 0.f, s_dir = 0.f;
    #pragma unroll
    for (int i = 0; i < 4; ++i) {
        float xo = to_[i + 2] - to_[i];
        float yo = fmaf(2.f, uo[i + 1], uo[i] + uo[i + 2]);
        float xt_ = tt_[i + 2] - tt_[i];
        float yt_ = fmaf(2.f, ut[i + 1], ut[i] + ut[i + 2]);

        float mago = __builtin_amdgcn_sqrtf(fmaf(xo, xo, fmaf(yo, yo, 1e-8f)));
        float magt = __builtin_amdgcn_sqrtf(fmaf(xt_, xt_, fmaf(yt_, yt_, 1e-8f)));
        float cross = yo * xt_ - xo * yt_;
        float dotp  = fmaf(xo, xt_, yo * yt_);
        float dd = abs_atan2_fast(cross, dotp);
        float w = wgt[i];
        s_w   += w;
        s_mag += w * fabsf(mago - magt);
        s_dir += dd * w;
    }

    // ---- block reduction (8 waves) ----
    #pragma unroll
    for (int o = 32; o > 0; o >>= 1) {
        s_w   += __shfl_down(s_w,   o, 64);
        s_mag += __shfl_down(s_mag, o, 64);
        s_dir += __shfl_down(s_dir, o, 64);
    }
    const int wid = tid >> 6;
    if ((tid & 63) == 0) { red[0][wid] = s_w; red[1][wid] = s_mag; red[2][wid] = s_dir; }
    __syncthreads();
    if (tid == 0) {
        float p0 = 0.f, p1 = 0.f, p2 = 0.f;
        #pragma unroll
        for (int k = 0; k < 8; ++k) { p0 += red[0][k]; p1 += red[1][k]; p2 += red[2][k]; }
        partials[bid]            = p0;
        partials[NBLK + bid]     = p1;
        partials[2 * NBLK + bid] = p2;
    }
}

__global__ __launch_bounds__(256) void egcl_finalize(
    const float* __restrict__ partials, float* __restrict__ out)
{
    __shared__ double red[3][4];
    const int tid = threadIdx.x;
    double s0 = 0.0, s1 = 0.0, s2 = 0.0;
    const float4* p0 = (const float4*)partials;
    const float4* p1 = (const float4*)(partials + NBLK);
    const float4* p2 = (const float4*)(partials + 2 * NBLK);
    for (int i = tid; i < NBLK / 4; i += 256) {
        float4 a = p0[i], b = p1[i], c = p2[i];
        s0 += (double)a.x + (double)a.y + (double)a.z + (double)a.w;
        s1 += (double)b.x + (double)b.y + (double)b.z + (double)b.w;
        s2 += (double)c.x + (double)c.y + (double)c.z + (double)c.w;
    }
    #pragma unroll
    for (int o = 32; o > 0; o >>= 1) {
        s0 += __shfl_down(s0, o, 64);
        s1 += __shfl_down(s1, o, 64);
        s2 += __shfl_down(s2, o, 64);
    }
    const int wid = tid >> 6;
    if ((tid & 63) == 0) { red[0][wid] = s0; red[1][wid] = s1; red[2][wid] = s2; }
    __syncthreads();
    if (tid == 0) {
        double Sw   = red[0][0] + red[0][1] + red[0][2] + red[0][3];
        double Smag = red[1][0] + red[1][1] + red[1][2] + red[1][3];
        double Sdir = red[2][0] + red[2][1] + red[2][2] + red[2][3];
        const double N = (double)NBC * HH * WW;
        double mag_loss = Smag / N;
        if (Sw > 0.0) mag_loss = mag_loss / (Sw / N + 1e-8);
        double dir_loss = Sdir;
        if (Sw > 0.0) dir_loss = Sdir / (Sw + 1e-8);
        out[0] = (float)(mag_loss + dir_loss);
    }
}

extern "C" void kernel_launch(void* const* d_in, const int* in_sizes, int n_in,
                              void* d_out, int out_size, void* d_ws, size_t ws_size,
                              hipStream_t stream)
{
    const float* outp = (const float*)d_in[0];
    const float* tgtp = (const float*)d_in[1];
    const int*   maskp = (const int*)d_in[2];
    float* partials = (float*)d_ws;

    egcl_fused<<<dim3(NBLK, 1, 1), 512, 0, stream>>>(outp, tgtp, maskp, partials);
    egcl_finalize<<<1, 256, 0, stream>>>(partials, (float*)d_out);
}

// Round 18
// 34.720 us; speedup vs baseline: 1.0361x; 1.0112x over previous
//
#include <hip/hip_runtime.h>
#include <math.h>

#define HH 512
#define WW 512
#define NBC 24          // B*C = 8*3
#define TH 64
#define TW 32
#define RAD 4
#define NXT (WW / TW)                 // 16 x-tiles
#define NYT (HH / TH)                 // 8 y-tiles
#define NBLK (NXT * NYT * NBC)        // 3072
#define PI_F 3.14159265358979323846f
#define SMW 36          // smh row stride (floats)
#define OTW 40          // oT/tT row stride; LDS col c <-> image col x0-4+c

// Gaussian taps: exp(-0.5*x^2)/sum, x=-4..4 (double-computed, f32-rounded;
// <=1 ulp vs jnp's f32 path).
__device__ __constant__ float GW[9] = {
    1.3383023e-04f, 4.4318484e-03f, 5.3990968e-02f, 2.4197073e-01f,
    3.9894228e-01f, 2.4197073e-01f, 5.3990968e-02f, 4.4318484e-03f,
    1.3383023e-04f
};

__device__ __forceinline__ int reflect_y(int gy)
{
    return (gy < 0) ? (-gy - 1) : ((gy >= HH) ? (2 * HH - 1 - gy) : gy);
}

// |atan2(y,x)| in [0,pi], branchless, ~1e-4 max error (threshold is 8.25e-2
// on a mean of [0,pi] values -> ample margin), NaN-free.
__device__ __forceinline__ float abs_atan2_fast(float y, float x)
{
    float ax = fabsf(x), ay = fabsf(y);
    float mx = fmaxf(ax, ay), mn = fminf(ax, ay);
    float t = mn * __builtin_amdgcn_rcpf(fmaxf(mx, 1e-30f));
    float s = t * t;
    float r = fmaf(s, fmaf(s, fmaf(s, -0.0851330f, 0.1801410f), -0.3302995f),
                   0.9998660f);
    r = r * t;                                  // atan(mn/mx) in [0, pi/4]
    r = (ay > ax) ? (0.5f * PI_F - r) : r;      // undo octant swap
    r = (x < 0.f) ? (PI_F - r) : r;             // quadrant
    return r;
}

__device__ __forceinline__ float4 hblur12(int4 a, int4 b, int4 c)
{
    float win[12] = {
        (float)a.x, (float)a.y, (float)a.z, (float)a.w,
        (float)b.x, (float)b.y, (float)b.z, (float)b.w,
        (float)c.x, (float)c.y, (float)c.z, (float)c.w };
    float s0 = 0.f, s1 = 0.f, s2 = 0.f, s3 = 0.f;
    #pragma unroll
    for (int j = 0; j < 9; ++j) {
        float gw = GW[j];
        s0 = fmaf(gw, win[j],     s0);
        s1 = fmaf(gw, win[j + 1], s1);
        s2 = fmaf(gw, win[j + 2], s2);
        s3 = fmaf(gw, win[j + 3], s3);
    }
    return make_float4(s0, s1, s2, s3);
}

// async 16B global -> LDS (wave-uniform LDS base + lane*16; per-lane gsrc)
__device__ __forceinline__ void gload_lds16(const float* gsrc, float* ldst)
{
    __builtin_amdgcn_global_load_lds(
        (const __attribute__((address_space(1))) void*)gsrc,
        (__attribute__((address_space(3))) void*)ldst, 16, 0, 0);
}

// 512 threads per 64x32 tile. o/t tiles staged via global_load_lds DMA
// (no VGPR round-trip, cannot be sunk by RA); mask H-blur VALU overlaps the
// DMA flight; one barrier.
__global__ __launch_bounds__(512) void egcl_fused(
    const float* __restrict__ outp,
    const float* __restrict__ tgtp,
    const int*   __restrict__ maskp,
    float*       __restrict__ partials)  // [3][NBLK]: w, mag, dir
{
    __shared__ __align__(16) float smh[TH + 8][SMW];  // 72 rows H-blurred mask
    __shared__ __align__(16) float oT[TH + 2][OTW];   // 66 rows x 40 cols
    __shared__ __align__(16) float tT[TH + 2][OTW];
    __shared__ float red[3][8];

    const int tid  = threadIdx.x;
    const int wv   = tid >> 6;
    const int lane = tid & 63;

    // XCD-aware bijective swizzle: each XCD gets 3 contiguous z-planes
    const int bid = (int)blockIdx.x;
    const int nb  = (bid & 7) * (NBLK / 8) + (bid >> 3);
    const int xt  = nb & 15;            // x-tile fastest -> row-of-tiles locality
    const int yt  = (nb >> 4) & 7;
    const int z   = nb >> 7;
    const int y0  = yt * TH;
    const int x0  = xt * TW;
    const size_t plane = (size_t)z * (HH * WW);
    const bool xedge = (x0 == 0) || (x0 == WW - TW);

    if (!xedge) {
        // ==== A: mask loads into regs (task0 all threads; task1 wave 0) ====
        const int r0  = tid >> 3;
        const int cg0 = (tid & 7) << 2;
        const int gy0 = reflect_y(y0 + r0 - RAD);
        const int* mr0 = maskp + plane + (size_t)gy0 * WW + x0 + cg0;
        int4 ma0 = *(const int4*)(mr0 - 4);
        int4 mb0 = *(const int4*)(mr0);
        int4 mc0 = *(const int4*)(mr0 + 4);
        const bool m2 = (tid < 64);
        int4 ma1 = ma0, mb1 = mb0, mc1 = mc0;
        int r1 = 0;
        if (m2) {
            r1 = 64 + (tid >> 3);
            const int gy1 = reflect_y(y0 + r1 - RAD);
            const int* mr1 = maskp + plane + (size_t)gy1 * WW + x0 + cg0;
            ma1 = *(const int4*)(mr1 - 4);
            mb1 = *(const int4*)(mr1);
            mc1 = *(const int4*)(mr1 + 4);
        }
        asm volatile("" ::: "memory");   // mask loads stay above the DMA

        // ==== B: issue o/t DMA. 660 float4 tasks per buffer, 11 segs/wave-set ====
        float* oTf = &oT[0][0];
        float* tTf = &tT[0][0];
        for (int seg = wv; seg < 11; seg += 8) {
            int t = (seg << 6) + lane;
            if (t < 660) {
                int rr = t / 10, g = t - 10 * rr;
                int gy = y0 + rr - 1;
                gy = (gy < 0) ? 0 : ((gy >= HH) ? (HH - 1) : gy);  // junk rows fixed later
                const size_t off = plane + (size_t)gy * WW + (x0 - 4 + (g << 2));
                gload_lds16(outp + off, oTf + (seg << 8));
                gload_lds16(tgtp + off, tTf + (seg << 8));
            }
        }

        // ==== C: mask H-blur + smh writes (overlaps DMA flight) ====
        *(float4*)&smh[r0][cg0] = hblur12(ma0, mb0, mc0);
        if (m2) *(float4*)&smh[r1][cg0] = hblur12(ma1, mb1, mc1);

        // ==== D: drain own DMAs, zero the (at most 2) out-of-range halo rows ====
        asm volatile("s_waitcnt vmcnt(0)" ::: "memory");
        if (y0 == 0 && wv == 0 && lane < 10) {            // row 0 in seg 0 (wave 0)
            *(float4*)&oT[0][lane << 2] = make_float4(0.f, 0.f, 0.f, 0.f);
            *(float4*)&tT[0][lane << 2] = make_float4(0.f, 0.f, 0.f, 0.f);
        }
        if (y0 + TH == HH && wv == 2 && lane < 10) {      // row 65 in seg 10 (wave 2)
            *(float4*)&oT[TH + 1][lane << 2] = make_float4(0.f, 0.f, 0.f, 0.f);
            *(float4*)&tT[TH + 1][lane << 2] = make_float4(0.f, 0.f, 0.f, 0.f);
        }
    } else {
        // ---- edge blocks: sequential scalar-reflect staging ----
        for (int i = tid; i < (TH + 8) * 8; i += 512) {
            int r = i >> 3, cg = (i & 7) << 2;
            int gy = reflect_y(y0 + r - RAD);
            const int* mrow = maskp + plane + (size_t)gy * WW;
            float win[12];
            #pragma unroll
            for (int k = 0; k < 12; ++k) {
                int gx = x0 + cg - 4 + k;
                gx = (gx < 0) ? (-gx - 1) : ((gx >= WW) ? (2 * WW - 1 - gx) : gx);
                win[k] = (float)mrow[gx];
            }
            float s0 = 0.f, s1 = 0.f, s2 = 0.f, s3 = 0.f;
            #pragma unroll
            for (int j = 0; j < 9; ++j) {
                float gw = GW[j];
                s0 = fmaf(gw, win[j],     s0);
                s1 = fmaf(gw, win[j + 1], s1);
                s2 = fmaf(gw, win[j + 2], s2);
                s3 = fmaf(gw, win[j + 3], s3);
            }
            *(float4*)&smh[r][cg] = make_float4(s0, s1, s2, s3);
        }
        for (int i = tid; i < 660; i += 512) {
            int rr = i / 10, g = i - 10 * rr;
            int gy = y0 + rr - 1;
            bool rowin = (gy >= 0) && (gy < HH);
            float a[4], b[4];
            #pragma unroll
            for (int k = 0; k < 4; ++k) {
                int gx = x0 - 4 + 4 * g + k;
                bool in = rowin && (gx >= 0) && (gx < WW);
                size_t idx = plane + (size_t)(rowin ? gy : 0) * WW + (in ? gx : 0);
                a[k] = in ? outp[idx] : 0.f;
                b[k] = in ? tgtp[idx] : 0.f;
            }
            *(float4*)&oT[rr][4 * g] = make_float4(a[0], a[1], a[2], a[3]);
            *(float4*)&tT[rr][4 * g] = make_float4(b[0], b[1], b[2], b[3]);
        }
    }
    __syncthreads();   // the ONLY mid-kernel barrier

    // ---- compute: thread owns 1 row x 4 cols ----
    const int r  = tid >> 3;            // 0..63
    const int c4 = (tid & 7) << 2;      // 0..28

    // V-blur over 9 smh rows -> weights
    float4 a0 = make_float4(0.f, 0.f, 0.f, 0.f);
    #pragma unroll
    for (int j = 0; j < 9; ++j) {
        float4 m = *(const float4*)&smh[r + j][c4];
        float gw = GW[j];
        a0.x = fmaf(gw, m.x, a0.x); a0.y = fmaf(gw, m.y, a0.y);
        a0.z = fmaf(gw, m.z, a0.z); a0.w = fmaf(gw, m.w, a0.w);
    }
    float wgt[4];
    {
        float smv[4] = {a0.x, a0.y, a0.z, a0.w};
        #pragma unroll
        for (int i = 0; i < 4; ++i) {
            float sm = fminf(fmaxf(smv[i], 0.f), 1.f);
            // w = 1 - 2|sm-0.5| is already in [0,1] for sm in [0,1];
            // the reference's second clip is a no-op.
            wgt[i] = fmaf(-2.f, fabsf(sm - 0.5f), 1.f);
        }
    }

    // Sobel windows: aligned f2+f4+f2 per row; W[j][idx] = LDS col c4+2+idx,
    // image col x0+c4-2+idx; window k (0..5) = idx k+1.
    float Wo[3][8], Wt[3][8];
    #pragma unroll
    for (int j = 0; j < 3; ++j) {
        *(float2*)&Wo[j][0] = *(const float2*)&oT[r + j][c4 + 2];
        *(float4*)&Wo[j][2] = *(const float4*)&oT[r + j][c4 + 4];
        *(float2*)&Wo[j][6] = *(const float2*)&oT[r + j][c4 + 8];
        *(float2*)&Wt[j][0] = *(const float2*)&tT[r + j][c4 + 2];
        *(float4*)&Wt[j][2] = *(const float4*)&tT[r + j][c4 + 4];
        *(float2*)&Wt[j][6] = *(const float2*)&tT[r + j][c4 + 8];
    }

    // separable Sobel: t = a+2b+c (gx = t[i+2]-t[i]); u = c-a (gy = u[i]+2u[i+1]+u[i+2])
    float to_[6], uo[6], tt_[6], ut[6];
    #pragma unroll
    for (int j = 0; j < 6; ++j) {
        to_[j] = fmaf(2.f, Wo[1][j + 1], Wo[0][j + 1] + Wo[2][j + 1]);
        uo[j]  = Wo[2][j + 1] - Wo[0][j + 1];
        tt_[j] = fmaf(2.f, Wt[1][j + 1], Wt[0][j + 1] + Wt[2][j + 1]);
        ut[j]  = Wt[2][j + 1] - Wt[0][j + 1];
    }

    float s_w = 0.f, s_mag = 0.f, s_dir = 0.f;
    #pragma unroll
    for (int i = 0; i < 4; ++i) {
        float xo = to_[i + 2] - to_[i];
        float yo = fmaf(2.f, uo[i + 1], uo[i] + uo[i + 2]);
        float xt_ = tt_[i + 2] - tt_[i];
        float yt_ = fmaf(2.f, ut[i + 1], ut[i] + ut[i + 2]);

        float mago = __builtin_amdgcn_sqrtf(fmaf(xo, xo, fmaf(yo, yo, 1e-8f)));
        float magt = __builtin_amdgcn_sqrtf(fmaf(xt_, xt_, fmaf(yt_, yt_, 1e-8f)));
        float cross = yo * xt_ - xo * yt_;
        float dotp  = fmaf(xo, xt_, yo * yt_);
        float dd = abs_atan2_fast(cross, dotp);
        float w = wgt[i];
        s_w   += w;
        s_mag += w * fabsf(mago - magt);
        s_dir += dd * w;
    }

    // ---- block reduction (8 waves) ----
    #pragma unroll
    for (int o = 32; o > 0; o >>= 1) {
        s_w   += __shfl_down(s_w,   o, 64);
        s_mag += __shfl_down(s_mag, o, 64);
        s_dir += __shfl_down(s_dir, o, 64);
    }
    const int wid = tid >> 6;
    if ((tid & 63) == 0) { red[0][wid] = s_w; red[1][wid] = s_mag; red[2][wid] = s_dir; }
    __syncthreads();
    if (tid == 0) {
        float p0 = 0.f, p1 = 0.f, p2 = 0.f;
        #pragma unroll
        for (int k = 0; k < 8; ++k) { p0 += red[0][k]; p1 += red[1][k]; p2 += red[2][k]; }
        partials[bid]            = p0;
        partials[NBLK + bid]     = p1;
        partials[2 * NBLK + bid] = p2;
    }
}

__global__ __launch_bounds__(256) void egcl_finalize(
    const float* __restrict__ partials, float* __restrict__ out)
{
    __shared__ double red[3][4];
    const int tid = threadIdx.x;
    double s0 = 0.0, s1 = 0.0, s2 = 0.0;
    const float4* p0 = (const float4*)partials;
    const float4* p1 = (const float4*)(partials + NBLK);
    const float4* p2 = (const float4*)(partials + 2 * NBLK);
    for (int i = tid; i < NBLK / 4; i += 256) {
        float4 a = p0[i], b = p1[i], c = p2[i];
        s0 += (double)a.x + (double)a.y + (double)a.z + (double)a.w;
        s1 += (double)b.x + (double)b.y + (double)b.z + (double)b.w;
        s2 += (double)c.x + (double)c.y + (double)c.z + (double)c.w;
    }
    #pragma unroll
    for (int o = 32; o > 0; o >>= 1) {
        s0 += __shfl_down(s0, o, 64);
        s1 += __shfl_down(s1, o, 64);
        s2 += __shfl_down(s2, o, 64);
    }
    const int wid = tid >> 6;
    if ((tid & 63) == 0) { red[0][wid] = s0; red[1][wid] = s1; red[2][wid] = s2; }
    __syncthreads();
    if (tid == 0) {
        double Sw   = red[0][0] + red[0][1] + red[0][2] + red[0][3];
        double Smag = red[1][0] + red[1][1] + red[1][2] + red[1][3];
        double Sdir = red[2][0] + red[2][1] + red[2][2] + red[2][3];
        const double N = (double)NBC * HH * WW;
        double mag_loss = Smag / N;
        if (Sw > 0.0) mag_loss = mag_loss / (Sw / N + 1e-8);
        double dir_loss = Sdir;
        if (Sw > 0.0) dir_loss = Sdir / (Sw + 1e-8);
        out[0] = (float)(mag_loss + dir_loss);
    }
}

extern "C" void kernel_launch(void* const* d_in, const int* in_sizes, int n_in,
                              void* d_out, int out_size, void* d_ws, size_t ws_size,
                              hipStream_t stream)
{
    const float* outp = (const float*)d_in[0];
    const float* tgtp = (const float*)d_in[1];
    const int*   maskp = (const int*)d_in[2];
    float* partials = (float*)d_ws;

    egcl_fused<<<dim3(NBLK, 1, 1), 512, 0, stream>>>(outp, tgtp, maskp, partials);
    egcl_finalize<<<1, 256, 0, stream>>>(partials, (float*)d_out);
}